// Round 12
// baseline (6228.776 us; speedup 1.0000x reference)
//
#include <hip/hip_runtime.h>
#include <hip/hip_bf16.h>
#include <stdint.h>

#define TT 512
#define HD 512
#define BB 32
#define MM (BB*TT)     // 16384 rows (b*T+t)
#define NG 3072        // 2 dirs * 3 gates * 512
#define WGD 8          // workgroups per direction
#define CPW 64         // h columns per workgroup

typedef short short8 __attribute__((ext_vector_type(8)));
typedef float f32x4 __attribute__((ext_vector_type(4)));
typedef float f32x2 __attribute__((ext_vector_type(2)));
typedef unsigned short u16;
typedef unsigned int u32;
typedef unsigned long long u64;

__device__ __forceinline__ u16 f2bf(float f) {
  __hip_bfloat16 h = __float2bfloat16(f);
  union { __hip_bfloat16 h; u16 u; } c; c.h = h; return c.u;
}
__device__ __forceinline__ float bf2f(u16 u) {
  union { u32 i; float f; } c; c.i = ((u32)u) << 16; return c.f;
}
__device__ __forceinline__ float sigmf(float x) {
  return 1.0f / (1.0f + __expf(-x));
}
__device__ __forceinline__ float tanhff(float x) {
  float a = __expf(2.0f * x);          // inf -> 1, 0 -> -1 : graceful
  return 1.0f - 2.0f / (a + 1.0f);
}

// ---------------- f32 -> bf16 convert ----------------
__global__ __launch_bounds__(256) void cvt_bf16(const float* __restrict__ in,
                                                u16* __restrict__ out, int n8) {
  int i = blockIdx.x * 256 + threadIdx.x;
  if (i >= n8) return;
  const float4* p = (const float4*)in;
  float4 a = p[2*i], b = p[2*i+1];
  union { short8 v; u16 u[8]; } o;
  o.u[0]=f2bf(a.x); o.u[1]=f2bf(a.y); o.u[2]=f2bf(a.z); o.u[3]=f2bf(a.w);
  o.u[4]=f2bf(b.x); o.u[5]=f2bf(b.y); o.u[6]=f2bf(b.z); o.u[7]=f2bf(b.w);
  ((short8*)out)[i] = o.v;
}

// ---------------- gx GEMM (unchanged) ----------------
__global__ __launch_bounds__(256) void gemm_gx(const u16* __restrict__ A,
                                               const u16* __restrict__ Bw,
                                               char* __restrict__ gxout,
                                               int K, int gxf32) {
  __shared__ __align__(16) u16 lA[128*32];
  __shared__ __align__(16) u16 lB[128*32];
  const int tid = threadIdx.x;
  const int lane = tid & 63;
  const int wid = tid >> 6;
  const int wr = wid >> 1, wc = wid & 1;
  const int bm = blockIdx.y * 128, bn = blockIdx.x * 128;
  const int col = lane & 15, kg = lane >> 4;

  f32x4 acc[4][4];
#pragma unroll
  for (int m = 0; m < 4; ++m)
#pragma unroll
    for (int n = 0; n < 4; ++n) acc[m][n] = (f32x4){0.f,0.f,0.f,0.f};

  const int nkt = K >> 5;
  for (int kt = 0; kt < nkt; ++kt) {
    short8 ra[2], rb[2];
    const int kb = kt * 32;
#pragma unroll
    for (int p = 0; p < 2; ++p) {
      int id = p*256 + tid;
      int row = id >> 2, c = id & 3;
      ra[p] = *(const short8*)(A  + (size_t)(bm+row)*K + kb + c*8);
      rb[p] = *(const short8*)(Bw + (size_t)(bn+row)*K + kb + c*8);
    }
    __syncthreads();
#pragma unroll
    for (int p = 0; p < 2; ++p) {
      int id = p*256 + tid;
      int row = id >> 2, c = id & 3;
      int off = row*64 + ((c ^ ((row>>1)&3))*16);
      *(short8*)((char*)lA + off) = ra[p];
      *(short8*)((char*)lB + off) = rb[p];
    }
    __syncthreads();
    short8 af[4], bf[4];
#pragma unroll
    for (int m = 0; m < 4; ++m) {
      int row = wr*64 + m*16 + col;
      af[m] = *(short8*)((char*)lA + row*64 + ((kg ^ ((row>>1)&3))*16));
    }
#pragma unroll
    for (int n = 0; n < 4; ++n) {
      int row = wc*64 + n*16 + col;
      bf[n] = *(short8*)((char*)lB + row*64 + ((kg ^ ((row>>1)&3))*16));
    }
#pragma unroll
    for (int m = 0; m < 4; ++m)
#pragma unroll
      for (int n = 0; n < 4; ++n)
        acc[m][n] = __builtin_amdgcn_mfma_f32_16x16x32_bf16(af[m], bf[n], acc[m][n], 0,0,0);
  }
#pragma unroll
  for (int m = 0; m < 4; ++m)
#pragma unroll
    for (int n = 0; n < 4; ++n)
#pragma unroll
      for (int r = 0; r < 4; ++r) {
        int rowg = bm + wr*64 + m*16 + kg*4 + r;
        int colg = bn + wc*64 + n*16 + col;
        float v = acc[m][n][r];
        if (gxf32) ((float*)gxout)[(size_t)rowg*NG + colg] = v;
        else       ((u16*)gxout)[(size_t)rowg*NG + colg] = f2bf(v);
      }
}

// ---------------- persistent BiGRU recurrence (1024-thr blocks, fan-in 8) ------
// grid = 16 WGs (1024 thr, 16 waves): dir = wg>>3, jb = wg&7 -> cols [jb*64,+64).
// Per-wave work IDENTICAL to R9 (1 weight pair, 32 MFMAs, 2KB slice read);
// only topology changes: 8 producers/dir, each wave polls ONE producer flag.
// Waves 0..11 MFMA (pair pi=wv: gate pi>>2, colblock pi&3). All 16 waves stage
// slices (producer wv&7, half wv>>3). Gates 2 cols/thread. Publish u32/thread.
__global__ __launch_bounds__(1024, 1) void bigru_rec(const char* __restrict__ gx,
                                                     const u16* __restrict__ whhb,
                                                     const float* __restrict__ b_ih,
                                                     const float* __restrict__ b_hh,
                                                     char* __restrict__ out,
                                                     u16* __restrict__ himg,   // [2][2][32][512]
                                                     u32* __restrict__ flags,  // [2][8] stride 16 dwords
                                                     int gxf32, int outf32) {
  const int wg = blockIdx.x;
  const int dir = wg >> 3;
  const int jb = wg & 7;
  const int tid = threadIdx.x;
  const int lane = tid & 63;
  const int wv = tid >> 6;
  const int col = lane & 15, kg = lane >> 4;

  __shared__ __align__(16) u16 hstage[32*512];     // 32 KB, swizzled
  __shared__ float gh[3][32][68];                  // 26 KB, padded
  __shared__ float bihs[3][64], bhhs[3][64];
  __shared__ u32 lctr;

  // --- one-time: w_hh B-fragments (waves 0..11: pair pi=wv -> gate, colblock) ---
  short8 bfrag[16];
  if (wv < 12) {
    const int g = wv >> 2, cb = wv & 3;
    const u16* wrow = whhb + (size_t)(dir*1536 + g*512 + jb*CPW + cb*16 + col) * 512;
#pragma unroll
    for (int kc = 0; kc < 16; ++kc)
      bfrag[kc] = *(const short8*)(wrow + kc*32 + kg*8);
  }
  if (tid < 192) {
    int g = tid >> 6, j = tid & 63;
    bihs[g][j] = b_ih[dir*1536 + g*512 + jb*CPW + j];
    bhhs[g][j] = b_hh[dir*1536 + g*512 + jb*CPW + j];
  }
  if (tid == 0) lctr = 0;
  __syncthreads();

  // gate ownership: thread -> (b = tid>>5, cols j0, j0+1), j0 = (tid&31)*2
  const int gb = tid >> 5, gj0 = (tid & 31) * 2;
  float hp0 = 0.f, hp1 = 0.f;

  u32* dirflags = flags + (size_t)dir * WGD * 16;
  u32* myflag = dirflags + (size_t)jb * 16;

  // slice staging: producer p = wv&7, half = wv>>3; lane -> row=lane>>1, which=lane&1
  const int sp = wv & 7, shalf = wv >> 3;
  const int srow = lane >> 1, swhich = lane & 1;
  const u32* fpw = dirflags + (size_t)sp * 16;

  for (int t = 0; t < TT; ++t) {
    const int tt = dir ? (TT - 1 - t) : t;
    const int par = t & 1;

    // --- gx[tt] -> registers (issued early; retire under poll) ---
    f32x2 xrF, xzF, xnF; u32 xrB=0, xzB=0, xnB=0;
    if (gxf32) {
      const float* gp = (const float*)gx + (size_t)(gb*TT+tt)*NG + dir*1536 + jb*CPW + gj0;
      xrF = *(const f32x2*)(gp);
      xzF = *(const f32x2*)(gp + 512);
      xnF = *(const f32x2*)(gp + 1024);
    } else {
      const u16* gp = (const u16*)gx + (size_t)(gb*TT+tt)*NG + dir*1536 + jb*CPW + gj0;
      xrB = *(const u32*)(gp);
      xzB = *(const u32*)(gp + 512);
      xnB = *(const u32*)(gp + 1024);
    }

    // --- poll own producer's flag, then read this wave's 2KB half-slice ---
    if (t > 0) {
      const u32 need = (u32)t;
      int it = 0;
      while (__hip_atomic_load(fpw, __ATOMIC_RELAXED, __HIP_MEMORY_SCOPE_AGENT) < need && it++ < (1<<24)) {}
    }
    __builtin_amdgcn_sched_barrier(0);
    asm volatile("" ::: "memory");   // pin slice loads AFTER the poll

    const u64* imgr = (const u64*)(himg + ((size_t)dir*2 + par) * 32 * 512);
    u64 v[4];
#pragma unroll
    for (int j = 0; j < 4; ++j)
      v[j] = __hip_atomic_load(imgr + srow*128 + sp*16 + shalf*8 + swhich*4 + j,
                               __ATOMIC_RELAXED, __HIP_MEMORY_SCOPE_AGENT);
#pragma unroll
    for (int j = 0; j < 4; ++j) {
      int d2 = sp*16 + shalf*8 + swhich*4 + j; int c = d2 >> 1;
      *(u64*)((char*)hstage + srow*1024 + (((c ^ (srow & 7)) << 4) | ((d2 & 1) << 3))) = v[j];
    }
    __syncthreads();   // (B) full image staged

    // --- MFMA: waves 0..11, 1 pair x 2 M-tiles x 16 kc ---
    if (wv < 12) {
      f32x4 acc0 = (f32x4){0.f,0.f,0.f,0.f};
      f32x4 acc1 = (f32x4){0.f,0.f,0.f,0.f};
#pragma unroll
      for (int kc = 0; kc < 16; ++kc) {
        int c = kc*4 + kg;
        short8 h0 = *(short8*)((char*)hstage + col*1024      + ((c ^ (col & 7)) << 4));
        short8 h1 = *(short8*)((char*)hstage + (16+col)*1024 + ((c ^ (col & 7)) << 4));
        acc0 = __builtin_amdgcn_mfma_f32_16x16x32_bf16(h0, bfrag[kc], acc0, 0,0,0);
        acc1 = __builtin_amdgcn_mfma_f32_16x16x32_bf16(h1, bfrag[kc], acc1, 0,0,0);
      }
      const int g = wv >> 2, cb = wv & 3;
#pragma unroll
      for (int r = 0; r < 4; ++r) {
        gh[g][kg*4 + r][cb*16 + col]      = acc0[r];
        gh[g][16 + kg*4 + r][cb*16 + col] = acc1[r];
      }
    }
    __syncthreads();   // (C) gh ready

    // --- gates: thread -> (b=gb, cols gj0, gj0+1) ---
    float hv0, hv1; u32 pv;
    {
      float xr0, xz0, xn0, xr1, xz1, xn1;
      if (gxf32) {
        xr0 = xrF.x; xz0 = xzF.x; xn0 = xnF.x;
        xr1 = xrF.y; xz1 = xzF.y; xn1 = xnF.y;
      } else {
        xr0 = bf2f((u16)(xrB & 0xffff)); xz0 = bf2f((u16)(xzB & 0xffff)); xn0 = bf2f((u16)(xnB & 0xffff));
        xr1 = bf2f((u16)(xrB >> 16));    xz1 = bf2f((u16)(xzB >> 16));    xn1 = bf2f((u16)(xnB >> 16));
      }
      float r0 = sigmf(xr0 + bihs[0][gj0]   + gh[0][gb][gj0]   + bhhs[0][gj0]);
      float z0 = sigmf(xz0 + bihs[1][gj0]   + gh[1][gb][gj0]   + bhhs[1][gj0]);
      float n0 = tanhff(xn0 + bihs[2][gj0]  + r0*(gh[2][gb][gj0] + bhhs[2][gj0]));
      hv0 = (1.f - z0)*n0 + z0*hp0;
      float r1 = sigmf(xr1 + bihs[0][gj0+1] + gh[0][gb][gj0+1] + bhhs[0][gj0+1]);
      float z1 = sigmf(xz1 + bihs[1][gj0+1] + gh[1][gb][gj0+1] + bhhs[1][gj0+1]);
      float n1 = tanhff(xn1 + bihs[2][gj0+1] + r1*(gh[2][gb][gj0+1] + bhhs[2][gj0+1]));
      hv1 = (1.f - z1)*n1 + z1*hp1;
      hp0 = hv0; hp1 = hv1;

      // publish h_new pair to next image (agent -> LLC)
      u32* img2 = (u32*)(himg + ((size_t)dir*2 + ((t + 1) & 1)) * 32 * 512);
      pv = (u32)f2bf(hv0) | ((u32)f2bf(hv1) << 16);
      __hip_atomic_store(img2 + gb*256 + jb*32 + (tid & 31), pv,
                         __ATOMIC_RELAXED, __HIP_MEMORY_SCOPE_AGENT);
    }

    // --- per-wave drain (parallel) -> LDS counter -> 16th wave releases WG flag ---
    asm volatile("s_waitcnt vmcnt(0)" ::: "memory");
    if (lane == 0) {
      u32 old = atomicAdd(&lctr, 1u);
      if (old == (u32)(t*16 + 15))
        __hip_atomic_store(myflag, (u32)(t + 1), __ATOMIC_RELAXED, __HIP_MEMORY_SCOPE_AGENT);
    }

    // --- out store after flag (drains during next poll window) ---
    {
      size_t oi = (size_t)(gb*TT + tt)*1024 + dir*512 + jb*CPW + gj0;
      if (outf32) {
        f32x2 ov; ov.x = hv0; ov.y = hv1;
        __builtin_nontemporal_store(ov, (f32x2*)((float*)out + oi));
      } else {
        __builtin_nontemporal_store(pv, (u32*)((u16*)out + oi));
      }
    }
  }
}

// ---------------- host ----------------
extern "C" void kernel_launch(void* const* d_in, const int* in_sizes, int n_in,
                              void* d_out, int out_size, void* d_ws, size_t ws_size,
                              hipStream_t stream) {
  (void)in_sizes; (void)n_in; (void)out_size;
  const float* x    = (const float*)d_in[0];
  const float* wih0 = (const float*)d_in[1];
  const float* whh0 = (const float*)d_in[2];
  const float* bih0 = (const float*)d_in[3];
  const float* bhh0 = (const float*)d_in[4];
  const float* wih1 = (const float*)d_in[5];
  const float* whh1 = (const float*)d_in[6];
  const float* bih1 = (const float*)d_in[7];
  const float* bhh1 = (const float*)d_in[8];

  char* ws = (char*)d_ws;
  size_t off = 0;
  auto alloc = [&](size_t bytes) { size_t o = off; off += (bytes + 255) & ~(size_t)255; return o; };
  size_t off_xb   = alloc((size_t)MM * 512 * 2);       // x bf16
  size_t off_wih0 = alloc((size_t)3072 * 512 * 2);
  size_t off_wih1 = alloc((size_t)3072 * 1024 * 2);
  size_t off_whh0 = alloc((size_t)3072 * 512 * 2);
  size_t off_whh1 = alloc((size_t)3072 * 512 * 2);
  size_t off_h0   = alloc((size_t)MM * 1024 * 2);      // layer-0 output bf16
  size_t off_sync = alloc(131072 + 4096);              // h images (128KB) + flags
  size_t off_gx   = off;                               // gx last
  int gxf32 = (ws_size >= off_gx + (size_t)MM * NG * 4) ? 1 : 0;

  u16* xb    = (u16*)(ws + off_xb);
  u16* wih0b = (u16*)(ws + off_wih0);
  u16* wih1b = (u16*)(ws + off_wih1);
  u16* whh0b = (u16*)(ws + off_whh0);
  u16* whh1b = (u16*)(ws + off_whh1);
  u16* h0b   = (u16*)(ws + off_h0);
  u16* himg  = (u16*)(ws + off_sync);
  u32* flags = (u32*)(ws + off_sync + 131072);
  char* gx   = ws + off_gx;

  cvt_bf16<<<4096, 256, 0, stream>>>(x,    xb,    MM*512/8);
  cvt_bf16<<<768,  256, 0, stream>>>(wih0, wih0b, 3072*512/8);
  cvt_bf16<<<1536, 256, 0, stream>>>(wih1, wih1b, 3072*1024/8);
  cvt_bf16<<<768,  256, 0, stream>>>(whh0, whh0b, 3072*512/8);
  cvt_bf16<<<768,  256, 0, stream>>>(whh1, whh1b, 3072*512/8);

  dim3 ggrid(NG/128, MM/128);   // (24, 128)

  // layer 0
  gemm_gx<<<ggrid, 256, 0, stream>>>(xb, wih0b, gx, 512, gxf32);
  (void)hipMemsetAsync(ws + off_sync, 0, 131072 + 4096, stream);
  bigru_rec<<<16, 1024, 0, stream>>>(gx, whh0b, bih0, bhh0, (char*)h0b, himg, flags, gxf32, 0);

  // layer 1
  gemm_gx<<<ggrid, 256, 0, stream>>>(h0b, wih1b, gx, 1024, gxf32);
  (void)hipMemsetAsync(ws + off_sync, 0, 131072 + 4096, stream);
  bigru_rec<<<16, 1024, 0, stream>>>(gx, whh1b, bih1, bhh1, (char*)d_out, himg, flags, gxf32, 1);
}

// Round 13
// 5245.230 us; speedup vs baseline: 1.1875x; 1.1875x over previous
//
#include <hip/hip_runtime.h>
#include <hip/hip_bf16.h>
#include <stdint.h>

#define TT 512
#define HD 512
#define BB 32
#define MM (BB*TT)     // 16384 rows (b*T+t)
#define NG 3072        // 2 dirs * 3 gates * 512
#define WGD 16         // workgroups per direction
#define CPW 32         // h columns per workgroup

typedef short short8 __attribute__((ext_vector_type(8)));
typedef float f32x4 __attribute__((ext_vector_type(4)));
typedef float f32x2 __attribute__((ext_vector_type(2)));
typedef unsigned short u16;
typedef unsigned int u32;
typedef unsigned long long u64;

__device__ __forceinline__ u16 f2bf(float f) {
  __hip_bfloat16 h = __float2bfloat16(f);
  union { __hip_bfloat16 h; u16 u; } c; c.h = h; return c.u;
}
__device__ __forceinline__ float bf2f(u16 u) {
  union { u32 i; float f; } c; c.i = ((u32)u) << 16; return c.f;
}
__device__ __forceinline__ float sigmf(float x) {
  return 1.0f / (1.0f + __expf(-x));
}
__device__ __forceinline__ float tanhff(float x) {
  float a = __expf(2.0f * x);          // inf -> 1, 0 -> -1 : graceful
  return 1.0f - 2.0f / (a + 1.0f);
}

// ---------------- f32 -> bf16 convert ----------------
__global__ __launch_bounds__(256) void cvt_bf16(const float* __restrict__ in,
                                                u16* __restrict__ out, int n8) {
  int i = blockIdx.x * 256 + threadIdx.x;
  if (i >= n8) return;
  const float4* p = (const float4*)in;
  float4 a = p[2*i], b = p[2*i+1];
  union { short8 v; u16 u[8]; } o;
  o.u[0]=f2bf(a.x); o.u[1]=f2bf(a.y); o.u[2]=f2bf(a.z); o.u[3]=f2bf(a.w);
  o.u[4]=f2bf(b.x); o.u[5]=f2bf(b.y); o.u[6]=f2bf(b.z); o.u[7]=f2bf(b.w);
  ((short8*)out)[i] = o.v;
}

// ---------------- gx GEMM (unchanged) ----------------
__global__ __launch_bounds__(256) void gemm_gx(const u16* __restrict__ A,
                                               const u16* __restrict__ Bw,
                                               char* __restrict__ gxout,
                                               int K, int gxf32) {
  __shared__ __align__(16) u16 lA[128*32];
  __shared__ __align__(16) u16 lB[128*32];
  const int tid = threadIdx.x;
  const int lane = tid & 63;
  const int wid = tid >> 6;
  const int wr = wid >> 1, wc = wid & 1;
  const int bm = blockIdx.y * 128, bn = blockIdx.x * 128;
  const int col = lane & 15, kg = lane >> 4;

  f32x4 acc[4][4];
#pragma unroll
  for (int m = 0; m < 4; ++m)
#pragma unroll
    for (int n = 0; n < 4; ++n) acc[m][n] = (f32x4){0.f,0.f,0.f,0.f};

  const int nkt = K >> 5;
  for (int kt = 0; kt < nkt; ++kt) {
    short8 ra[2], rb[2];
    const int kb = kt * 32;
#pragma unroll
    for (int p = 0; p < 2; ++p) {
      int id = p*256 + tid;
      int row = id >> 2, c = id & 3;
      ra[p] = *(const short8*)(A  + (size_t)(bm+row)*K + kb + c*8);
      rb[p] = *(const short8*)(Bw + (size_t)(bn+row)*K + kb + c*8);
    }
    __syncthreads();
#pragma unroll
    for (int p = 0; p < 2; ++p) {
      int id = p*256 + tid;
      int row = id >> 2, c = id & 3;
      int off = row*64 + ((c ^ ((row>>1)&3))*16);
      *(short8*)((char*)lA + off) = ra[p];
      *(short8*)((char*)lB + off) = rb[p];
    }
    __syncthreads();
    short8 af[4], bf[4];
#pragma unroll
    for (int m = 0; m < 4; ++m) {
      int row = wr*64 + m*16 + col;
      af[m] = *(short8*)((char*)lA + row*64 + ((kg ^ ((row>>1)&3))*16));
    }
#pragma unroll
    for (int n = 0; n < 4; ++n) {
      int row = wc*64 + n*16 + col;
      bf[n] = *(short8*)((char*)lB + row*64 + ((kg ^ ((row>>1)&3))*16));
    }
#pragma unroll
    for (int m = 0; m < 4; ++m)
#pragma unroll
      for (int n = 0; n < 4; ++n)
        acc[m][n] = __builtin_amdgcn_mfma_f32_16x16x32_bf16(af[m], bf[n], acc[m][n], 0,0,0);
  }
#pragma unroll
  for (int m = 0; m < 4; ++m)
#pragma unroll
    for (int n = 0; n < 4; ++n)
#pragma unroll
      for (int r = 0; r < 4; ++r) {
        int rowg = bm + wr*64 + m*16 + kg*4 + r;
        int colg = bn + wc*64 + n*16 + col;
        float v = acc[m][n][r];
        if (gxf32) ((float*)gxout)[(size_t)rowg*NG + colg] = v;
        else       ((u16*)gxout)[(size_t)rowg*NG + colg] = f2bf(v);
      }
}

// ---------------- persistent BiGRU recurrence (tagged-data sync, no flags) -----
// grid = 32 WGs (512 thr, 8 waves): dir = wg>>4, jb = wg&15 -> cols [jb*32,+32).
// h image: [2 dir][2 buf][32 b][256] u64, each u64 = {tag:u32 (hi), 2xbf16 (lo)}.
// Publish at step t writes tag t+1 with the data in ONE atomic store; consumers
// poll their slice loads until all tags == t (detection fused with payload —
// one LLC round trip). No flags, no vmcnt drain, no LDS counter. Skew stays
// 1-step bounded: passing the step-t poll proves all producers issued tag-t
// stores, which (loads consumed before stores issued, per program order)
// proves all step t-1 reads completed before any overwrite.
__global__ __launch_bounds__(512, 2) void bigru_rec(const char* __restrict__ gx,
                                                    const u16* __restrict__ whhb,
                                                    const float* __restrict__ b_ih,
                                                    const float* __restrict__ b_hh,
                                                    char* __restrict__ out,
                                                    u64* __restrict__ himg,   // [2][2][32][256] u64
                                                    int gxf32, int outf32) {
  const int wg = blockIdx.x;
  const int dir = wg >> 4;
  const int jb = wg & 15;
  const int tid = threadIdx.x;
  const int lane = tid & 63;
  const int wv = tid >> 6;
  const int col = lane & 15, kg = lane >> 4;

  __shared__ __align__(16) u16 hstage[32*512];     // 32 KB, swizzled
  __shared__ float gh[3][32][33];                  // padded
  __shared__ float bihs[3][32], bhhs[3][32];

  // --- one-time: w_hh B-fragments (waves 0..5: gate g=wv>>1, half ch=wv&1) ---
  short8 bfrag[16];
  if (wv < 6) {
    const int g = wv >> 1, ch = wv & 1;
    const u16* wrow = whhb + (size_t)(dir*1536 + g*512 + jb*CPW + ch*16 + col) * 512;
#pragma unroll
    for (int kc = 0; kc < 16; ++kc)
      bfrag[kc] = *(const short8*)(wrow + kc*32 + kg*8);
  }
  if (tid < 96) {
    int g = tid >> 5, j = tid & 31;
    bihs[g][j] = b_ih[dir*1536 + g*512 + jb*CPW + j];
    bhhs[g][j] = b_hh[dir*1536 + g*512 + jb*CPW + j];
  }
  __syncthreads();

  const int gb = tid >> 4, gj0 = (tid & 15) * 2;
  float hp0 = 0.f, hp1 = 0.f;

  // slice read: wave w owns producers p0=w, p1=w+8; lane -> row=lane>>1, half=lane&1
  const int srow = lane >> 1, shalf = lane & 1;
  const int p0 = wv, p1 = wv + 8;

  for (int t = 0; t < TT; ++t) {
    const int tt = dir ? (TT - 1 - t) : t;
    const int par = t & 1;

    // --- gx[tt] -> registers (issued early; retire under poll) ---
    f32x2 xrF, xzF, xnF; u32 xrB=0, xzB=0, xnB=0;
    if (gxf32) {
      const float* gp = (const float*)gx + (size_t)(gb*TT+tt)*NG + dir*1536 + jb*CPW + gj0;
      xrF = *(const f32x2*)(gp);
      xzF = *(const f32x2*)(gp + 512);
      xnF = *(const f32x2*)(gp + 1024);
    } else {
      const u16* gp = (const u16*)gx + (size_t)(gb*TT+tt)*NG + dir*1536 + jb*CPW + gj0;
      xrB = *(const u32*)(gp);
      xzB = *(const u32*)(gp + 512);
      xnB = *(const u32*)(gp + 1024);
    }

    // --- fused poll+read: re-load slice u64s until all tags == t ---
    const u64* imgr = himg + ((size_t)dir*2 + par) * 32 * 256;
    u64 v0[8], v1[8];
    {
      const u32 need = (u32)t;
      int it = 0;
      while (it++ < (1 << 22)) {
#pragma unroll
        for (int j = 0; j < 8; ++j) {
          v0[j] = __hip_atomic_load(imgr + srow*256 + p0*16 + shalf*8 + j,
                                    __ATOMIC_RELAXED, __HIP_MEMORY_SCOPE_AGENT);
          v1[j] = __hip_atomic_load(imgr + srow*256 + p1*16 + shalf*8 + j,
                                    __ATOMIC_RELAXED, __HIP_MEMORY_SCOPE_AGENT);
        }
        bool ok = true;
#pragma unroll
        for (int j = 0; j < 8; ++j)
          ok = ok && ((u32)(v0[j] >> 32) == need) && ((u32)(v1[j] >> 32) == need);
        if (__all(ok)) break;
      }
    }

    // --- LDS writes: combine pairs (low u32 of two u64s) -> swizzled u64 ---
#pragma unroll
    for (int k = 0; k < 4; ++k) {
      u64 d = (v0[2*k] & 0xffffffffull) | (v0[2*k+1] << 32);
      int d2 = p0*8 + shalf*4 + k; int c = d2 >> 1;
      *(u64*)((char*)hstage + srow*1024 + (((c ^ (srow & 7)) << 4) | ((d2 & 1) << 3))) = d;
    }
#pragma unroll
    for (int k = 0; k < 4; ++k) {
      u64 d = (v1[2*k] & 0xffffffffull) | (v1[2*k+1] << 32);
      int d2 = p1*8 + shalf*4 + k; int c = d2 >> 1;
      *(u64*)((char*)hstage + srow*1024 + (((c ^ (srow & 7)) << 4) | ((d2 & 1) << 3))) = d;
    }
    __syncthreads();   // (B) full image staged

    // --- MFMA: gh[g][b][jloc] over K=512 (waves 0..5) ---
    if (wv < 6) {
      const int g = wv >> 1, ch = wv & 1;
      f32x4 acc0 = (f32x4){0.f,0.f,0.f,0.f};
      f32x4 acc1 = (f32x4){0.f,0.f,0.f,0.f};
#pragma unroll
      for (int kc = 0; kc < 16; ++kc) {
        int c = kc*4 + kg;
        short8 a0 = *(short8*)((char*)hstage + col*1024      + ((c ^ (col & 7)) << 4));
        short8 a1 = *(short8*)((char*)hstage + (16+col)*1024 + ((c ^ (col & 7)) << 4));
        acc0 = __builtin_amdgcn_mfma_f32_16x16x32_bf16(a0, bfrag[kc], acc0, 0,0,0);
        acc1 = __builtin_amdgcn_mfma_f32_16x16x32_bf16(a1, bfrag[kc], acc1, 0,0,0);
      }
#pragma unroll
      for (int r = 0; r < 4; ++r) {
        gh[g][kg*4 + r][ch*16 + col]      = acc0[r];
        gh[g][16 + kg*4 + r][ch*16 + col] = acc1[r];
      }
    }
    __syncthreads();   // (C) gh ready

    // --- gates: thread -> (b=gb, cols gj0, gj0+1) ---
    float hv0, hv1; u32 pv;
    {
      float xr0, xz0, xn0, xr1, xz1, xn1;
      if (gxf32) {
        xr0 = xrF.x; xz0 = xzF.x; xn0 = xnF.x;
        xr1 = xrF.y; xz1 = xzF.y; xn1 = xnF.y;
      } else {
        xr0 = bf2f((u16)(xrB & 0xffff)); xz0 = bf2f((u16)(xzB & 0xffff)); xn0 = bf2f((u16)(xnB & 0xffff));
        xr1 = bf2f((u16)(xrB >> 16));    xz1 = bf2f((u16)(xzB >> 16));    xn1 = bf2f((u16)(xnB >> 16));
      }
      float r0 = sigmf(xr0 + bihs[0][gj0]   + gh[0][gb][gj0]   + bhhs[0][gj0]);
      float z0 = sigmf(xz0 + bihs[1][gj0]   + gh[1][gb][gj0]   + bhhs[1][gj0]);
      float n0 = tanhff(xn0 + bihs[2][gj0]  + r0*(gh[2][gb][gj0] + bhhs[2][gj0]));
      hv0 = (1.f - z0)*n0 + z0*hp0;
      float r1 = sigmf(xr1 + bihs[0][gj0+1] + gh[0][gb][gj0+1] + bhhs[0][gj0+1]);
      float z1 = sigmf(xz1 + bihs[1][gj0+1] + gh[1][gb][gj0+1] + bhhs[1][gj0+1]);
      float n1 = tanhff(xn1 + bihs[2][gj0+1] + r1*(gh[2][gb][gj0+1] + bhhs[2][gj0+1]));
      hv1 = (1.f - z1)*n1 + z1*hp1;
      hp0 = hv0; hp1 = hv1;

      // publish tagged pair (tag = t+1 in high u32; fire-and-forget)
      u64* img2 = himg + ((size_t)dir*2 + ((t + 1) & 1)) * 32 * 256;
      pv = (u32)f2bf(hv0) | ((u32)f2bf(hv1) << 16);
      u64 tagged = (u64)pv | ((u64)(u32)(t + 1) << 32);
      __hip_atomic_store(img2 + gb*256 + jb*16 + (tid & 15), tagged,
                         __ATOMIC_RELAXED, __HIP_MEMORY_SCOPE_AGENT);
    }

    // --- out store (no sync tail; drains in background) ---
    {
      size_t oi = (size_t)(gb*TT + tt)*1024 + dir*512 + jb*CPW + gj0;
      if (outf32) {
        f32x2 ov; ov.x = hv0; ov.y = hv1;
        __builtin_nontemporal_store(ov, (f32x2*)((float*)out + oi));
      } else {
        __builtin_nontemporal_store(pv, (u32*)((u16*)out + oi));
      }
    }
  }
}

// ---------------- host ----------------
extern "C" void kernel_launch(void* const* d_in, const int* in_sizes, int n_in,
                              void* d_out, int out_size, void* d_ws, size_t ws_size,
                              hipStream_t stream) {
  (void)in_sizes; (void)n_in; (void)out_size;
  const float* x    = (const float*)d_in[0];
  const float* wih0 = (const float*)d_in[1];
  const float* whh0 = (const float*)d_in[2];
  const float* bih0 = (const float*)d_in[3];
  const float* bhh0 = (const float*)d_in[4];
  const float* wih1 = (const float*)d_in[5];
  const float* whh1 = (const float*)d_in[6];
  const float* bih1 = (const float*)d_in[7];
  const float* bhh1 = (const float*)d_in[8];

  char* ws = (char*)d_ws;
  size_t off = 0;
  auto alloc = [&](size_t bytes) { size_t o = off; off += (bytes + 255) & ~(size_t)255; return o; };
  size_t off_xb   = alloc((size_t)MM * 512 * 2);       // x bf16
  size_t off_wih0 = alloc((size_t)3072 * 512 * 2);
  size_t off_wih1 = alloc((size_t)3072 * 1024 * 2);
  size_t off_whh0 = alloc((size_t)3072 * 512 * 2);
  size_t off_whh1 = alloc((size_t)3072 * 512 * 2);
  size_t off_h0   = alloc((size_t)MM * 1024 * 2);      // layer-0 output bf16
  size_t off_sync = alloc(262144);                     // tagged h images [2][2][32][256]u64
  size_t off_gx   = off;                               // gx last
  int gxf32 = (ws_size >= off_gx + (size_t)MM * NG * 4) ? 1 : 0;

  u16* xb    = (u16*)(ws + off_xb);
  u16* wih0b = (u16*)(ws + off_wih0);
  u16* wih1b = (u16*)(ws + off_wih1);
  u16* whh0b = (u16*)(ws + off_whh0);
  u16* whh1b = (u16*)(ws + off_whh1);
  u16* h0b   = (u16*)(ws + off_h0);
  u64* himg  = (u64*)(ws + off_sync);
  char* gx   = ws + off_gx;

  cvt_bf16<<<4096, 256, 0, stream>>>(x,    xb,    MM*512/8);
  cvt_bf16<<<768,  256, 0, stream>>>(wih0, wih0b, 3072*512/8);
  cvt_bf16<<<1536, 256, 0, stream>>>(wih1, wih1b, 3072*1024/8);
  cvt_bf16<<<768,  256, 0, stream>>>(whh0, whh0b, 3072*512/8);
  cvt_bf16<<<768,  256, 0, stream>>>(whh1, whh1b, 3072*512/8);

  dim3 ggrid(NG/128, MM/128);   // (24, 128)

  // layer 0
  gemm_gx<<<ggrid, 256, 0, stream>>>(xb, wih0b, gx, 512, gxf32);
  (void)hipMemsetAsync(ws + off_sync, 0, 262144, stream);
  bigru_rec<<<32, 512, 0, stream>>>(gx, whh0b, bih0, bhh0, (char*)h0b, himg, gxf32, 0);

  // layer 1
  gemm_gx<<<ggrid, 256, 0, stream>>>(h0b, wih1b, gx, 1024, gxf32);
  (void)hipMemsetAsync(ws + off_sync, 0, 262144, stream);
  bigru_rec<<<32, 512, 0, stream>>>(gx, whh1b, bih1, bhh1, (char*)d_out, himg, gxf32, 1);
}

// Round 14
// 4492.778 us; speedup vs baseline: 1.3864x; 1.1675x over previous
//
#include <hip/hip_runtime.h>
#include <hip/hip_bf16.h>
#include <stdint.h>

#define TT 512
#define HD 512
#define BB 32
#define MM (BB*TT)     // 16384 rows (b*T+t)
#define NG 3072        // 2 dirs * 3 gates * 512
#define WGD 16         // workgroups per direction
#define CPW 32         // h columns per workgroup

typedef short short8 __attribute__((ext_vector_type(8)));
typedef float f32x4 __attribute__((ext_vector_type(4)));
typedef float f32x2 __attribute__((ext_vector_type(2)));
typedef unsigned short u16;
typedef unsigned int u32;
typedef unsigned long long u64;

__device__ __forceinline__ u16 f2bf(float f) {
  __hip_bfloat16 h = __float2bfloat16(f);
  union { __hip_bfloat16 h; u16 u; } c; c.h = h; return c.u;
}
__device__ __forceinline__ float bf2f(u16 u) {
  union { u32 i; float f; } c; c.i = ((u32)u) << 16; return c.f;
}
__device__ __forceinline__ float sigmf(float x) {
  return 1.0f / (1.0f + __expf(-x));
}
__device__ __forceinline__ float tanhff(float x) {
  float a = __expf(2.0f * x);          // inf -> 1, 0 -> -1 : graceful
  return 1.0f - 2.0f / (a + 1.0f);
}

// ---------------- f32 -> bf16 convert ----------------
__global__ __launch_bounds__(256) void cvt_bf16(const float* __restrict__ in,
                                                u16* __restrict__ out, int n8) {
  int i = blockIdx.x * 256 + threadIdx.x;
  if (i >= n8) return;
  const float4* p = (const float4*)in;
  float4 a = p[2*i], b = p[2*i+1];
  union { short8 v; u16 u[8]; } o;
  o.u[0]=f2bf(a.x); o.u[1]=f2bf(a.y); o.u[2]=f2bf(a.z); o.u[3]=f2bf(a.w);
  o.u[4]=f2bf(b.x); o.u[5]=f2bf(b.y); o.u[6]=f2bf(b.z); o.u[7]=f2bf(b.w);
  ((short8*)out)[i] = o.v;
}

// ---------------- gx GEMM (unchanged) ----------------
__global__ __launch_bounds__(256) void gemm_gx(const u16* __restrict__ A,
                                               const u16* __restrict__ Bw,
                                               char* __restrict__ gxout,
                                               int K, int gxf32) {
  __shared__ __align__(16) u16 lA[128*32];
  __shared__ __align__(16) u16 lB[128*32];
  const int tid = threadIdx.x;
  const int lane = tid & 63;
  const int wid = tid >> 6;
  const int wr = wid >> 1, wc = wid & 1;
  const int bm = blockIdx.y * 128, bn = blockIdx.x * 128;
  const int col = lane & 15, kg = lane >> 4;

  f32x4 acc[4][4];
#pragma unroll
  for (int m = 0; m < 4; ++m)
#pragma unroll
    for (int n = 0; n < 4; ++n) acc[m][n] = (f32x4){0.f,0.f,0.f,0.f};

  const int nkt = K >> 5;
  for (int kt = 0; kt < nkt; ++kt) {
    short8 ra[2], rb[2];
    const int kb = kt * 32;
#pragma unroll
    for (int p = 0; p < 2; ++p) {
      int id = p*256 + tid;
      int row = id >> 2, c = id & 3;
      ra[p] = *(const short8*)(A  + (size_t)(bm+row)*K + kb + c*8);
      rb[p] = *(const short8*)(Bw + (size_t)(bn+row)*K + kb + c*8);
    }
    __syncthreads();
#pragma unroll
    for (int p = 0; p < 2; ++p) {
      int id = p*256 + tid;
      int row = id >> 2, c = id & 3;
      int off = row*64 + ((c ^ ((row>>1)&3))*16);
      *(short8*)((char*)lA + off) = ra[p];
      *(short8*)((char*)lB + off) = rb[p];
    }
    __syncthreads();
    short8 af[4], bf[4];
#pragma unroll
    for (int m = 0; m < 4; ++m) {
      int row = wr*64 + m*16 + col;
      af[m] = *(short8*)((char*)lA + row*64 + ((kg ^ ((row>>1)&3))*16));
    }
#pragma unroll
    for (int n = 0; n < 4; ++n) {
      int row = wc*64 + n*16 + col;
      bf[n] = *(short8*)((char*)lB + row*64 + ((kg ^ ((row>>1)&3))*16));
    }
#pragma unroll
    for (int m = 0; m < 4; ++m)
#pragma unroll
      for (int n = 0; n < 4; ++n)
        acc[m][n] = __builtin_amdgcn_mfma_f32_16x16x32_bf16(af[m], bf[n], acc[m][n], 0,0,0);
  }
#pragma unroll
  for (int m = 0; m < 4; ++m)
#pragma unroll
    for (int n = 0; n < 4; ++n)
#pragma unroll
      for (int r = 0; r < 4; ++r) {
        int rowg = bm + wr*64 + m*16 + kg*4 + r;
        int colg = bn + wc*64 + n*16 + col;
        float v = acc[m][n][r];
        if (gxf32) ((float*)gxout)[(size_t)rowg*NG + colg] = v;
        else       ((u16*)gxout)[(size_t)rowg*NG + colg] = f2bf(v);
      }
}

// ---------------- persistent BiGRU recurrence (R9 + plain out stores) ----------
// grid = 32 WGs (512 thr, 8 waves): dir = wg>>4, jb = wg&15 -> cols [jb*32,+32).
// Wave w polls producers p=w and p=w+8 individually and reads each 2KB slice the
// moment its flag lands (sched_barrier+memory clobber pins loads after poll).
// KEY FIX vs R9: out stores are PLAIN cached stores, not nontemporal. vmcnt
// retires IN ORDER, so step t's NT out store (HBM ack ~1us) was delaying step
// t+1's poll-load consumption. Plain stores ack at L2 (~200cyc).
__global__ __launch_bounds__(512, 2) void bigru_rec(const char* __restrict__ gx,
                                                    const u16* __restrict__ whhb,
                                                    const float* __restrict__ b_ih,
                                                    const float* __restrict__ b_hh,
                                                    char* __restrict__ out,
                                                    u16* __restrict__ himg,   // [2][2][32][512]
                                                    u32* __restrict__ flags,  // [2][16] stride 16 dwords
                                                    int gxf32, int outf32) {
  const int wg = blockIdx.x;
  const int dir = wg >> 4;
  const int jb = wg & 15;
  const int tid = threadIdx.x;
  const int lane = tid & 63;
  const int wv = tid >> 6;
  const int col = lane & 15, kg = lane >> 4;

  __shared__ __align__(16) u16 hstage[32*512];     // 32 KB, swizzled
  __shared__ float gh[3][32][33];                  // padded: no bank conflicts
  __shared__ float bihs[3][32], bhhs[3][32];
  __shared__ u32 lctr;

  // --- one-time: w_hh B-fragments (waves 0..5: gate g=wv>>1, half ch=wv&1) ---
  short8 bfrag[16];
  if (wv < 6) {
    const int g = wv >> 1, ch = wv & 1;
    const u16* wrow = whhb + (size_t)(dir*1536 + g*512 + jb*CPW + ch*16 + col) * 512;
#pragma unroll
    for (int kc = 0; kc < 16; ++kc)
      bfrag[kc] = *(const short8*)(wrow + kc*32 + kg*8);
  }
  if (tid < 96) {
    int g = tid >> 5, j = tid & 31;
    bihs[g][j] = b_ih[dir*1536 + g*512 + jb*CPW + j];
    bhhs[g][j] = b_hh[dir*1536 + g*512 + jb*CPW + j];
  }
  if (tid == 0) lctr = 0;
  __syncthreads();

  const int gb = tid >> 4, gj0 = (tid & 15) * 2;
  float hp0 = 0.f, hp1 = 0.f;

  u32* dirflags = flags + (size_t)dir * WGD * 16;
  u32* myflag = dirflags + (size_t)jb * 16;

  // slice-read lane mapping: row = lane>>1, 32B group g4 = (lane&1)*4
  const int srow = lane >> 1, sg4 = (lane & 1) * 4;
  const int p0 = wv, p1 = wv + 8;
  const u32* fp0 = dirflags + (size_t)p0 * 16;
  const u32* fp1 = dirflags + (size_t)p1 * 16;

  for (int t = 0; t < TT; ++t) {
    const int tt = dir ? (TT - 1 - t) : t;
    const int par = t & 1;

    // --- gx[tt] -> registers (issued early; retire under poll) ---
    f32x2 xrF, xzF, xnF; u32 xrB=0, xzB=0, xnB=0;
    if (gxf32) {
      const float* gp = (const float*)gx + (size_t)(gb*TT+tt)*NG + dir*1536 + jb*CPW + gj0;
      xrF = *(const f32x2*)(gp);
      xzF = *(const f32x2*)(gp + 512);
      xnF = *(const f32x2*)(gp + 1024);
    } else {
      const u16* gp = (const u16*)gx + (size_t)(gb*TT+tt)*NG + dir*1536 + jb*CPW + gj0;
      xrB = *(const u32*)(gp);
      xzB = *(const u32*)(gp + 512);
      xnB = *(const u32*)(gp + 1024);
    }

    // --- pipelined per-producer poll + slice read (2KB each) ---
    const u64* imgr = (const u64*)(himg + ((size_t)dir*2 + par) * 32 * 512);
    u64 v0[4], v1[4];
    if (t > 0) {
      const u32 need = (u32)t;
      int it = 0;
      while (__hip_atomic_load(fp0, __ATOMIC_RELAXED, __HIP_MEMORY_SCOPE_AGENT) < need && it++ < (1<<24)) {}
    }
    __builtin_amdgcn_sched_barrier(0);
    asm volatile("" ::: "memory");   // pin slice loads AFTER the poll (compiler fence)
#pragma unroll
    for (int j = 0; j < 4; ++j)
      v0[j] = __hip_atomic_load(imgr + srow*128 + p0*8 + sg4 + j, __ATOMIC_RELAXED, __HIP_MEMORY_SCOPE_AGENT);
    if (t > 0) {
      const u32 need = (u32)t;
      int it = 0;
      while (__hip_atomic_load(fp1, __ATOMIC_RELAXED, __HIP_MEMORY_SCOPE_AGENT) < need && it++ < (1<<24)) {}
    }
    __builtin_amdgcn_sched_barrier(0);
    asm volatile("" ::: "memory");   // pin slice loads AFTER the poll (compiler fence)
#pragma unroll
    for (int j = 0; j < 4; ++j)
      v1[j] = __hip_atomic_load(imgr + srow*128 + p1*8 + sg4 + j, __ATOMIC_RELAXED, __HIP_MEMORY_SCOPE_AGENT);

    // --- LDS writes: slices (swizzled) ---
#pragma unroll
    for (int j = 0; j < 4; ++j) {
      int d2 = p0*8 + sg4 + j; int c = d2 >> 1;
      *(u64*)((char*)hstage + srow*1024 + (((c ^ (srow & 7)) << 4) | ((d2 & 1) << 3))) = v0[j];
    }
#pragma unroll
    for (int j = 0; j < 4; ++j) {
      int d2 = p1*8 + sg4 + j; int c = d2 >> 1;
      *(u64*)((char*)hstage + srow*1024 + (((c ^ (srow & 7)) << 4) | ((d2 & 1) << 3))) = v1[j];
    }
    __syncthreads();   // (B) hstage staged by all waves

    // --- MFMA: gh[g][b][jloc] over K=512 (waves 0..5) ---
    if (wv < 6) {
      const int g = wv >> 1, ch = wv & 1;
      f32x4 acc0 = (f32x4){0.f,0.f,0.f,0.f};
      f32x4 acc1 = (f32x4){0.f,0.f,0.f,0.f};
#pragma unroll
      for (int kc = 0; kc < 16; ++kc) {
        int c = kc*4 + kg;
        short8 a0 = *(short8*)((char*)hstage + col*1024      + ((c ^ (col & 7)) << 4));
        short8 a1 = *(short8*)((char*)hstage + (16+col)*1024 + ((c ^ (col & 7)) << 4));
        acc0 = __builtin_amdgcn_mfma_f32_16x16x32_bf16(a0, bfrag[kc], acc0, 0,0,0);
        acc1 = __builtin_amdgcn_mfma_f32_16x16x32_bf16(a1, bfrag[kc], acc1, 0,0,0);
      }
#pragma unroll
      for (int r = 0; r < 4; ++r) {
        gh[g][kg*4 + r][ch*16 + col]      = acc0[r];
        gh[g][16 + kg*4 + r][ch*16 + col] = acc1[r];
      }
    }
    __syncthreads();   // (C)

    // --- gates: thread -> (b=gb, j=gj0, gj0+1) ---
    float hv0, hv1; u32 pv;
    {
      float xr0, xz0, xn0, xr1, xz1, xn1;
      if (gxf32) {
        xr0 = xrF.x; xz0 = xzF.x; xn0 = xnF.x;
        xr1 = xrF.y; xz1 = xzF.y; xn1 = xnF.y;
      } else {
        xr0 = bf2f((u16)(xrB & 0xffff)); xz0 = bf2f((u16)(xzB & 0xffff)); xn0 = bf2f((u16)(xnB & 0xffff));
        xr1 = bf2f((u16)(xrB >> 16));    xz1 = bf2f((u16)(xzB >> 16));    xn1 = bf2f((u16)(xnB >> 16));
      }
      float r0 = sigmf(xr0 + bihs[0][gj0]   + gh[0][gb][gj0]   + bhhs[0][gj0]);
      float z0 = sigmf(xz0 + bihs[1][gj0]   + gh[1][gb][gj0]   + bhhs[1][gj0]);
      float n0 = tanhff(xn0 + bihs[2][gj0]  + r0*(gh[2][gb][gj0] + bhhs[2][gj0]));
      hv0 = (1.f - z0)*n0 + z0*hp0;
      float r1 = sigmf(xr1 + bihs[0][gj0+1] + gh[0][gb][gj0+1] + bhhs[0][gj0+1]);
      float z1 = sigmf(xz1 + bihs[1][gj0+1] + gh[1][gb][gj0+1] + bhhs[1][gj0+1]);
      float n1 = tanhff(xn1 + bihs[2][gj0+1] + r1*(gh[2][gb][gj0+1] + bhhs[2][gj0+1]));
      hv1 = (1.f - z1)*n1 + z1*hp1;
      hp0 = hv0; hp1 = hv1;

      // publish h_new pair to next image (agent -> LLC)
      u32* img2 = (u32*)(himg + ((size_t)dir*2 + ((t + 1) & 1)) * 32 * 512);
      pv = (u32)f2bf(hv0) | ((u32)f2bf(hv1) << 16);
      __hip_atomic_store(img2 + gb*256 + jb*16 + (tid & 15), pv,
                         __ATOMIC_RELAXED, __HIP_MEMORY_SCOPE_AGENT);
    }

    // --- per-wave drain (parallel) -> LDS counter -> 8th wave releases WG flag ---
    asm volatile("s_waitcnt vmcnt(0)" ::: "memory");
    if (lane == 0) {
      u32 old = atomicAdd(&lctr, 1u);
      if (old == (u32)(t*8 + 7))
        __hip_atomic_store(myflag, (u32)(t + 1), __ATOMIC_RELAXED, __HIP_MEMORY_SCOPE_AGENT);
    }

    // --- out store after flag: PLAIN cached store (L2 ack ~200cyc; a NT store's
    //     HBM ack would stall next step's poll via in-order vmcnt retirement) ---
    {
      size_t oi = (size_t)(gb*TT + tt)*1024 + dir*512 + jb*CPW + gj0;
      if (outf32) {
        f32x2 ov; ov.x = hv0; ov.y = hv1;
        *(f32x2*)((float*)out + oi) = ov;
      } else {
        *(u32*)((u16*)out + oi) = pv;
      }
    }
  }
}

// ---------------- host ----------------
extern "C" void kernel_launch(void* const* d_in, const int* in_sizes, int n_in,
                              void* d_out, int out_size, void* d_ws, size_t ws_size,
                              hipStream_t stream) {
  (void)in_sizes; (void)n_in; (void)out_size;
  const float* x    = (const float*)d_in[0];
  const float* wih0 = (const float*)d_in[1];
  const float* whh0 = (const float*)d_in[2];
  const float* bih0 = (const float*)d_in[3];
  const float* bhh0 = (const float*)d_in[4];
  const float* wih1 = (const float*)d_in[5];
  const float* whh1 = (const float*)d_in[6];
  const float* bih1 = (const float*)d_in[7];
  const float* bhh1 = (const float*)d_in[8];

  char* ws = (char*)d_ws;
  size_t off = 0;
  auto alloc = [&](size_t bytes) { size_t o = off; off += (bytes + 255) & ~(size_t)255; return o; };
  size_t off_xb   = alloc((size_t)MM * 512 * 2);       // x bf16
  size_t off_wih0 = alloc((size_t)3072 * 512 * 2);
  size_t off_wih1 = alloc((size_t)3072 * 1024 * 2);
  size_t off_whh0 = alloc((size_t)3072 * 512 * 2);
  size_t off_whh1 = alloc((size_t)3072 * 512 * 2);
  size_t off_h0   = alloc((size_t)MM * 1024 * 2);      // layer-0 output bf16
  size_t off_sync = alloc(131072 + 4096);              // h images (128KB) + flags
  size_t off_gx   = off;                               // gx last
  int gxf32 = (ws_size >= off_gx + (size_t)MM * NG * 4) ? 1 : 0;

  u16* xb    = (u16*)(ws + off_xb);
  u16* wih0b = (u16*)(ws + off_wih0);
  u16* wih1b = (u16*)(ws + off_wih1);
  u16* whh0b = (u16*)(ws + off_whh0);
  u16* whh1b = (u16*)(ws + off_whh1);
  u16* h0b   = (u16*)(ws + off_h0);
  u16* himg  = (u16*)(ws + off_sync);
  u32* flags = (u32*)(ws + off_sync + 131072);
  char* gx   = ws + off_gx;

  cvt_bf16<<<4096, 256, 0, stream>>>(x,    xb,    MM*512/8);
  cvt_bf16<<<768,  256, 0, stream>>>(wih0, wih0b, 3072*512/8);
  cvt_bf16<<<1536, 256, 0, stream>>>(wih1, wih1b, 3072*1024/8);
  cvt_bf16<<<768,  256, 0, stream>>>(whh0, whh0b, 3072*512/8);
  cvt_bf16<<<768,  256, 0, stream>>>(whh1, whh1b, 3072*512/8);

  dim3 ggrid(NG/128, MM/128);   // (24, 128)

  // layer 0
  gemm_gx<<<ggrid, 256, 0, stream>>>(xb, wih0b, gx, 512, gxf32);
  (void)hipMemsetAsync(ws + off_sync, 0, 131072 + 4096, stream);
  bigru_rec<<<32, 512, 0, stream>>>(gx, whh0b, bih0, bhh0, (char*)h0b, himg, flags, gxf32, 0);

  // layer 1
  gemm_gx<<<ggrid, 256, 0, stream>>>(h0b, wih1b, gx, 1024, gxf32);
  (void)hipMemsetAsync(ws + off_sync, 0, 131072 + 4096, stream);
  bigru_rec<<<32, 512, 0, stream>>>(gx, whh1b, bih1, bhh1, (char*)d_out, himg, flags, gxf32, 1);
}